// Round 1
// baseline (178.898 us; speedup 1.0000x reference)
//
#include <hip/hip_runtime.h>
#include <hip/hip_bf16.h>

// Embedding gather: out[t, :] = e[token_ids[t], :]
// token_ids: (2,4096) int32 -> 8192 tokens
// e: (32000, 1024) float32
// out: (2, 4096, 1024) float32
//
// One block per token, 256 threads, each thread moves one float4
// (256 * 4 floats = 1024 floats = one row).

#define DIM 1024

__global__ __launch_bounds__(256) void embedding_gather_kernel(
    const int* __restrict__ ids,
    const float* __restrict__ e,
    float* __restrict__ out)
{
    const int token = blockIdx.x;
    const int row = ids[token];  // wave-uniform -> scalar load

    const float4* __restrict__ src =
        (const float4*)(e + (size_t)row * DIM);
    float4* __restrict__ dst =
        (float4*)(out + (size_t)token * DIM);

    dst[threadIdx.x] = src[threadIdx.x];
}

extern "C" void kernel_launch(void* const* d_in, const int* in_sizes, int n_in,
                              void* d_out, int out_size, void* d_ws, size_t ws_size,
                              hipStream_t stream)
{
    const int* ids = (const int*)d_in[0];     // (2,4096) int32
    const float* e = (const float*)d_in[1];   // (32000,1024) fp32
    float* out = (float*)d_out;               // (2,4096,1024) fp32

    const int n_tokens = in_sizes[0];         // 8192

    embedding_gather_kernel<<<n_tokens, 256, 0, stream>>>(ids, e, out);
}

// Round 3
// 178.046 us; speedup vs baseline: 1.0048x; 1.0048x over previous
//
#include <hip/hip_runtime.h>
#include <hip/hip_bf16.h>

// Embedding gather: out[t, :] = e[token_ids[t], :]
// token_ids: (2,4096) int32 -> 8192 tokens
// e: (32000, 1024) float32
// out: (2, 4096, 1024) float32
//
// 4 tokens per 256-thread block (grid = 2048): each thread moves one 16B
// vector per token, 4 independent gathers in flight per wave (ILP),
// non-temporal stores so the write-once output doesn't evict embedding
// rows from L2. Native ext_vector_type (not HIP float4) so
// __builtin_nontemporal_store accepts it.

#define DIM 1024
#define TOK_PER_BLOCK 4

typedef float f32x4 __attribute__((ext_vector_type(4)));

__global__ __launch_bounds__(256) void embedding_gather_kernel(
    const int* __restrict__ ids,
    const float* __restrict__ e,
    float* __restrict__ out,
    int n_tokens)
{
    const int t0 = blockIdx.x * TOK_PER_BLOCK;
    const int tid = threadIdx.x;

    // Wave-uniform row indices (all 256 threads of the block share each token)
    int rows[TOK_PER_BLOCK];
#pragma unroll
    for (int i = 0; i < TOK_PER_BLOCK; ++i)
        rows[i] = ids[t0 + i];

    // 4 independent 16B gather loads in flight
    f32x4 v[TOK_PER_BLOCK];
#pragma unroll
    for (int i = 0; i < TOK_PER_BLOCK; ++i) {
        const f32x4* src = (const f32x4*)(e + (size_t)rows[i] * DIM);
        v[i] = src[tid];
    }

    // Non-temporal stores: output is write-once, keep it out of L2
#pragma unroll
    for (int i = 0; i < TOK_PER_BLOCK; ++i) {
        f32x4* dst = (f32x4*)(out + (size_t)(t0 + i) * DIM);
        __builtin_nontemporal_store(v[i], dst + tid);
    }
}

extern "C" void kernel_launch(void* const* d_in, const int* in_sizes, int n_in,
                              void* d_out, int out_size, void* d_ws, size_t ws_size,
                              hipStream_t stream)
{
    const int* ids = (const int*)d_in[0];     // (2,4096) int32
    const float* e = (const float*)d_in[1];   // (32000,1024) fp32
    float* out = (float*)d_out;               // (2,4096,1024) fp32

    const int n_tokens = in_sizes[0];         // 8192
    const int grid = n_tokens / TOK_PER_BLOCK; // 2048

    embedding_gather_kernel<<<grid, 256, 0, stream>>>(ids, e, out, n_tokens);
}